// Round 20
// baseline (5035.048 us; speedup 1.0000x reference)
//
#include <hip/hip_runtime.h>

// ---------------------------------------------------------------------------
// LSTM scan, B=64 L=512 D=1024. Round 20 = R19 (passed, 3.58ms) with a
// K-sliced barrier: leaves regrouped by K-range (leaf = ord>>2, so leaf j
// holds the 4 WGs producing cols [256j,256j+256)); each wave polls ONLY its
// own K-slice leaf at the TOP of the step (per-wave acquire fence), then
// gathers+MFMAs immediately -- overlapping straggler wait with compute.
// Whole-WG tail barrier deleted. Skew stays <=1 step: a WG's 4 waves cover
// all 4 leaves, so its store still implies all WGs finished the prior step.
// Protocol primitives unchanged (ACQ_REL arrive / relaxed poll / agent
// acquire fence); geometry, LDS(64512B), offsets identical to R19.
// ---------------------------------------------------------------------------

typedef float    f32x4 __attribute__((ext_vector_type(4)));
typedef _Float16 half8 __attribute__((ext_vector_type(8)));
typedef _Float16 half4 __attribute__((ext_vector_type(4)));

#define AS1 __attribute__((address_space(1)))
#define AS3 __attribute__((address_space(3)))

#define B_  64
#define L_  512
#define D_  1024
#define N3_ 3072

// ws layout (bytes) -- identical to R13/R18/R19
#define WKT_OFF   0LL          // f16 [3072][1024]   6291456
#define WRT_OFF   6291456LL    // f16 [3072][1024]   6291456
#define XH_OFF    12582912LL   // f16 [B*L][1024]   67108864
#define H16_OFF   79691776LL   // f16 [2][64][1024]   262144
#define BAR_OFF   79953920LL   // unsigned[1024]        4096
#define XPROJ_OFF 79958016LL   // f16 [B*L][3072]   201326592

__device__ __forceinline__ float sigmoidf_fast(float x) {
  return __builtin_amdgcn_rcpf(1.f + __builtin_amdgcn_exp2f(-1.4426950408889634f * x));
}
__device__ __forceinline__ float tanhf_fast(float x) {
  return 1.f - 2.f * __builtin_amdgcn_rcpf(1.f + __builtin_amdgcn_exp2f(2.8853900817779268f * x));
}

// pinned (non-rematerializable) cached 16B load
#define ALOAD(dst, addr) \
  asm volatile("global_load_dwordx4 %0, %1, off" : "=v"(dst) : "v"(addr))
#define VMCNT0() asm volatile("s_waitcnt vmcnt(0)" ::: "memory")

__device__ __forceinline__ void gload_lds16(const void* g, void* l) {
  __builtin_amdgcn_global_load_lds((const AS1 unsigned int*)g,
                                   (AS3 unsigned int*)l, 16, 0, 0);
}

// ---------------- prep: zero the barrier space (kernel, replay-proven) -----
__global__ void zero_bar(unsigned* __restrict__ bar) {
  bar[blockIdx.x * 256 + threadIdx.x] = 0u;
}

// ---------------- prep: transpose + f32->f16 (Wk and Wr) -------------------
__global__ __launch_bounds__(256) void transpose_f16(
    const float* __restrict__ Wk, const float* __restrict__ Wr,
    _Float16* __restrict__ WkT, _Float16* __restrict__ WrT)
{
  __shared__ float tile[32][33];
  int b = blockIdx.x;
  const float* in = Wk; _Float16* outp = WkT;
  if (b >= 3072) { b -= 3072; in = Wr; outp = WrT; }
  const int n0 = (b % 96) * 32;
  const int k0 = (b / 96) * 32;
  const int tx = threadIdx.x & 31, ty = threadIdx.x >> 5;
#pragma unroll
  for (int i = 0; i < 32; i += 8)
    tile[ty + i][tx] = in[(size_t)(k0 + ty + i) * N3_ + n0 + tx];
  __syncthreads();
#pragma unroll
  for (int i = 0; i < 32; i += 8)
    outp[(size_t)(n0 + ty + i) * D_ + k0 + tx] = (_Float16)tile[tx][ty + i];
}

// ---------------- prep: x -> f16, h0 -> BOTH h16 buffers -------------------
__global__ void convert_inputs(const f32x4* __restrict__ x, const f32x4* __restrict__ h0,
                               half4* __restrict__ xh, half4* __restrict__ h16a,
                               half4* __restrict__ h16b)
{
  const int NX = (B_ * L_ * D_) / 4;
  const int NH = (B_ * D_) / 4;
  for (int i = blockIdx.x * blockDim.x + threadIdx.x; i < NX + NH;
       i += gridDim.x * blockDim.x) {
    if (i < NX) {
      xh[i] = __builtin_convertvector(x[i], half4);
    } else {
      half4 v = __builtin_convertvector(h0[i - NX], half4);
      h16a[i - NX] = v;
      h16b[i - NX] = v;
    }
  }
}

// ---------------- xproj GEMM (R7-fixed swizzle, replay-proven) -------------
__global__ __launch_bounds__(256) void gemm_xproj(
    const _Float16* __restrict__ A,    // [32768][1024]
    const _Float16* __restrict__ BT,   // [3072][1024]
    _Float16* __restrict__ C)          // [32768][3072] f16
{
  __shared__ _Float16 As[128 * 32];
  __shared__ _Float16 Bs[128 * 32];
  const int tid = threadIdx.x, wave = tid >> 6, lane = tid & 63;
  const int mt = blockIdx.x / 24, ntile = blockIdx.x % 24;
  const int m0 = mt * 128, n0 = ntile * 128;
  const int l15 = lane & 15, l4h = lane >> 4;
  const int wm = (wave >> 1) * 64, wn = (wave & 1) * 64;

  const int c0i = wave * 2;
  const int lrow = lane >> 2;                       // 0..15 within chunk
  const int skel = 8 * ((lane & 3) ^ (lrow & 3));   // 2-bit XOR, in-bounds

  f32x4 acc[4][4];
#pragma unroll
  for (int i = 0; i < 4; ++i)
#pragma unroll
    for (int j = 0; j < 4; ++j) { f32x4 z = {0.f,0.f,0.f,0.f}; acc[i][j] = z; }

  for (int kk = 0; kk < 32; ++kk) {
    __syncthreads();
#pragma unroll
    for (int i = 0; i < 2; ++i) {
      const int c = c0i + i;
      const int row = c * 16 + lrow;
      gload_lds16(A  + (((size_t)(m0 + row)) << 10) + (kk << 5) + skel, &As[c << 9]);
      gload_lds16(BT + (((size_t)(n0 + row)) << 10) + (kk << 5) + skel, &Bs[c << 9]);
    }
    __syncthreads();
    half8 af[4], bf[4];
#pragma unroll
    for (int i = 0; i < 4; ++i) {
      const int ar = wm + i * 16 + l15;
      af[i] = *(const half8*)&As[(ar << 5) + ((l4h ^ (ar & 3)) << 3)];
      const int br = wn + i * 16 + l15;
      bf[i] = *(const half8*)&Bs[(br << 5) + ((l4h ^ (br & 3)) << 3)];
    }
#pragma unroll
    for (int i = 0; i < 4; ++i)
#pragma unroll
      for (int j = 0; j < 4; ++j)
        acc[i][j] = __builtin_amdgcn_mfma_f32_16x16x32_f16(af[i], bf[j], acc[i][j], 0, 0, 0);
  }
#pragma unroll
  for (int i = 0; i < 4; ++i) {
    const int row = m0 + wm + i * 16 + l4h * 4;
#pragma unroll
    for (int j = 0; j < 4; ++j) {
      const int col = n0 + wn + j * 16 + l15;
      _Float16* cp = C + (size_t)row * N3_ + col;
#pragma unroll
      for (int r = 0; r < 4; ++r)
        __builtin_nontemporal_store((_Float16)acc[i][j][r], cp + (size_t)r * N3_);
    }
  }
}

// ---------------- persistent scan ------------------------------------------
// 64 WGs = 4 groups x 16 d-slices (64 cols); 512 threads = 8 waves.
// Wave w: ks = w&3 (K-slice 256), ch = w>>2 (32-col half).
// Barrier per group: 4 leaf lines by K-RANGE (leaf = ord>>2; leaf j = the 4
// WGs producing cols [256j,256j+256)). Arrive: ACQ_REL RMW own leaf.
// Wait (top of step, PER WAVE): poll leaf[ks] only + per-wave acquire fence.
__global__ __launch_bounds__(512, 2) void lstm_scan(
    const _Float16* __restrict__ WrT,   // [3072][1024]
    const _Float16* __restrict__ xproj, // [B*L][3072]
    const float*    __restrict__ c0,    // [64][1024]
    float*          __restrict__ out,   // [64][512][1024]
    _Float16*       __restrict__ h16,   // [2][64][1024]
    unsigned*       __restrict__ bar)
{
  const int tid = threadIdx.x, wave = tid >> 6, lane = tid & 63;
  const int bid = blockIdx.x;
  const int grp = bid & 3;           // b-tile group (independent scan)
  const int ord = bid >> 2;          // d-slice 0..15
  const int b0 = grp * 16;
  const int d0 = ord * 64;
  const int l15 = lane & 15, l4h = lane >> 4;
  const int ks = wave & 3, ch = wave >> 2;
  const int kbase = ks * 256;

  unsigned* const gbase = bar + grp * 256;
  unsigned* const leafp = gbase + (ord >> 2) * 16;  // arrive: own K-range leaf
  unsigned* const pollp = gbase + ks * 16;          // wait: my K-slice's leaf

  // ---- stationary Wr fragments: 2 nt blocks x 3 gates x 8 kt = 192 regs ----
  half8 Wrf[2][3][8];
#pragma unroll
  for (int nt = 0; nt < 2; ++nt)
#pragma unroll
    for (int g = 0; g < 3; ++g) {
      const _Float16* rr = WrT +
          (size_t)(g * D_ + d0 + ch * 32 + nt * 16 + l15) * D_ + kbase + l4h * 8;
#pragma unroll
      for (int kt = 0; kt < 8; ++kt) ALOAD(Wrf[nt][g][kt], rr + kt * 32);
    }
  VMCNT0();

  // final-reduce mapping: thread -> (rb, c) with two col-halves H=0,1
  const int rb = tid >> 5;       // batch 0..15
  const int c  = tid & 31;       // col within half
  const int ntc = c >> 4, rd16 = c & 15;
  float cc[2];
  cc[0] = c0[(size_t)(b0 + rb) * D_ + d0 + c];
  cc[1] = c0[(size_t)(b0 + rb) * D_ + d0 + 32 + c];

  __shared__ float part[4][4][48][21];   // pad 21 (R19): 2-way banks, free

  const size_t hoff    = (size_t)(b0 + l15) * D_ + kbase + l4h * 8;
  const size_t outidx0 = ((size_t)(b0 + rb) * L_) * D_ + d0 + c;
  const size_t hidx0   = (size_t)(b0 + rb) * D_ + d0 + c;
  const _Float16* xpbase = xproj + ((size_t)(b0 + rb) * L_) * N3_ + d0 + c;

  _Float16* hc = h16;            // h_t (both buffers pre-initialized with h0)
  _Float16* hn = h16 + B_ * D_;  // h_{t+1}

  // prologue: xp for t=0 (cold one-time reads): [gate][H]
  float xpv[3][2];
#pragma unroll
  for (int g = 0; g < 3; ++g) {
    xpv[g][0] = (float)xpbase[(size_t)g * D_];
    xpv[g][1] = (float)xpbase[(size_t)g * D_ + 32];
  }

  for (int t = 0; t < L_; ++t) {
    // ---- per-wave wait: poll MY K-slice's leaf, then wave acquire fence ----
    if (t > 0) {
      if (lane == 0) {
        const unsigned tgt = 4u * (unsigned)t;   // 4 WGs/leaf, t arrives each
        while (__hip_atomic_load(pollp, __ATOMIC_RELAXED,
                                 __HIP_MEMORY_SCOPE_AGENT) < tgt) {
          __builtin_amdgcn_s_sleep(1);
        }
      }
      __builtin_amdgcn_fence(__ATOMIC_ACQUIRE, "agent");  // per-wave inv
    }

    // ---- h fragments (plain vector loads; my K-slice is now fresh) ----
    half8 af[8];
    const _Float16* hrow = hc + hoff;
#pragma unroll
    for (int kt = 0; kt < 8; ++kt) af[kt] = *(const half8*)(hrow + kt * 32);

    f32x4 acc[2][3];
#pragma unroll
    for (int nt = 0; nt < 2; ++nt)
#pragma unroll
      for (int g = 0; g < 3; ++g) { f32x4 z = {0.f,0.f,0.f,0.f}; acc[nt][g] = z; }
#pragma unroll
    for (int kt = 0; kt < 8; ++kt)
#pragma unroll
      for (int nt = 0; nt < 2; ++nt)
#pragma unroll
        for (int g = 0; g < 3; ++g)
          acc[nt][g] = __builtin_amdgcn_mfma_f32_16x16x32_f16(af[kt], Wrf[nt][g][kt], acc[nt][g], 0, 0, 0);

    // ---- cross-wave reduce via LDS ----
#pragma unroll
    for (int nt = 0; nt < 2; ++nt)
#pragma unroll
      for (int g = 0; g < 3; ++g)
        *(f32x4*)&part[ks][ch * 2 + nt][g * 16 + l15][l4h * 4] = acc[nt][g];
    __syncthreads();   // S1: all part writes done before reduce reads

    float hv[2];
#pragma unroll
    for (int H = 0; H < 2; ++H) {
      const int e = H * 2 + ntc;
      float fv = xpv[0][H], ov = xpv[1][H], gv = xpv[2][H];
#pragma unroll
      for (int k = 0; k < 4; ++k) {
        fv += part[k][e][rd16][rb];
        ov += part[k][e][16 + rd16][rb];
        gv += part[k][e][32 + rd16][rb];
      }
      const float sf = sigmoidf_fast(fv);
      cc[H] = cc[H] * sf + (1.f - sf) * tanhf_fast(gv);
      hv[H] = sigmoidf_fast(ov) * tanhf_fast(cc[H]);
    }

    hn[hidx0]      = (_Float16)hv[0];   // plain cached stores (R10: NT hurts)
    hn[hidx0 + 32] = (_Float16)hv[1];

    // ---- arrive gate: S2 (vmcnt0; also fences part vs next-step writes) ----
    __syncthreads();
    if (tid == 0)
      __hip_atomic_fetch_add(leafp, 1u, __ATOMIC_ACQ_REL, __HIP_MEMORY_SCOPE_AGENT);

    // ---- shadow: NT out stores + xp[t+1] prefetch (pre-poll, constant) ----
    {
      float* op = out + outidx0 + (size_t)t * D_;
      __builtin_nontemporal_store(hv[0], op);
      __builtin_nontemporal_store(hv[1], op + 32);
    }
    if (t + 1 < L_) {
      const _Float16* xp = xpbase + (size_t)(t + 1) * N3_;
#pragma unroll
      for (int g = 0; g < 3; ++g) {
        xpv[g][0] = (float)xp[(size_t)g * D_];
        xpv[g][1] = (float)xp[(size_t)g * D_ + 32];
      }
    }
    __builtin_amdgcn_sched_barrier(0);   // keep shadow work issued here

    _Float16* tmp = hc; hc = hn; hn = tmp;
  }
}

// ---------------------------------------------------------------------------
extern "C" void kernel_launch(void* const* d_in, const int* in_sizes, int n_in,
                              void* d_out, int out_size, void* d_ws, size_t ws_size,
                              hipStream_t stream) {
  const float* x  = (const float*)d_in[0];
  const float* Wk = (const float*)d_in[1];
  const float* Wr = (const float*)d_in[2];
  const float* c0 = (const float*)d_in[3];
  const float* h0 = (const float*)d_in[4];
  float* out = (float*)d_out;

  char* ws = (char*)d_ws;
  _Float16* WkT   = (_Float16*)(ws + WKT_OFF);
  _Float16* WrT   = (_Float16*)(ws + WRT_OFF);
  _Float16* xh    = (_Float16*)(ws + XH_OFF);
  _Float16* h16   = (_Float16*)(ws + H16_OFF);
  unsigned* bar   = (unsigned*)(ws + BAR_OFF);
  _Float16* xproj = (_Float16*)(ws + XPROJ_OFF);

  hipLaunchKernelGGL(zero_bar, dim3(4), dim3(256), 0, stream, bar);
  hipLaunchKernelGGL(transpose_f16, dim3(6144), dim3(256), 0, stream,
                     Wk, Wr, WkT, WrT);
  hipLaunchKernelGGL(convert_inputs, dim3(2048), dim3(256), 0, stream,
                     (const f32x4*)x, (const f32x4*)h0,
                     (half4*)xh, (half4*)h16, (half4*)(h16 + B_ * D_));
  hipLaunchKernelGGL(gemm_xproj, dim3(6144), dim3(256), 0, stream,
                     xh, WkT, xproj);

  void* kargs[6] = {(void*)&WrT, (void*)&xproj, (void*)&c0,
                    (void*)&out, (void*)&h16, (void*)&bar};
  hipLaunchCooperativeKernel((void*)lstm_scan, dim3(64), dim3(512), kargs, 0, stream);
}

// Round 21
// 3551.686 us; speedup vs baseline: 1.4177x; 1.4177x over previous
//
#include <hip/hip_runtime.h>

// ---------------------------------------------------------------------------
// LSTM scan, B=64 L=512 D=1024. Round 21: NEW STRUCTURE CLASS.
// 512 sequential step-kernels in the captured graph -- the kernel boundary
// IS the grid-wide barrier (HW-guaranteed coherence, zero atomics/fences).
// Persistent-kernel sync floor was ~6.4us/step (R19); graph node dispatch
// ~2-3us would beat it. Step kernel = R12's compute body (256 WGs x 256thr,
// 16b x 16d tiles, 4 waves x K-slice 256), Wr re-read from L2 each step.
//   - h ping-pong via alternating kernel args (t parity)
//   - c updated IN-PLACE (each (b,d) owned by exactly one thread);
//     re-seeded from c0 every kernel_launch (determinism)
//   - xproj precomputed by the R7-proven GEMM
// ---------------------------------------------------------------------------

typedef float    f32x4 __attribute__((ext_vector_type(4)));
typedef _Float16 half8 __attribute__((ext_vector_type(8)));
typedef _Float16 half4 __attribute__((ext_vector_type(4)));

#define AS1 __attribute__((address_space(1)))
#define AS3 __attribute__((address_space(3)))

#define B_  64
#define L_  512
#define D_  1024
#define N3_ 3072

// ws layout (bytes)
#define WKT_OFF   0LL          // f16 [3072][1024]   6291456
#define WRT_OFF   6291456LL    // f16 [3072][1024]   6291456
#define XH_OFF    12582912LL   // f16 [B*L][1024]   67108864
#define H16_OFF   79691776LL   // f16 [2][64][1024]   262144
#define CST_OFF   79953920LL   // f32 [64][1024]      262144
#define XPROJ_OFF 80216064LL   // f16 [B*L][3072]   201326592

__device__ __forceinline__ float sigmoidf_fast(float x) {
  return __builtin_amdgcn_rcpf(1.f + __builtin_amdgcn_exp2f(-1.4426950408889634f * x));
}
__device__ __forceinline__ float tanhf_fast(float x) {
  return 1.f - 2.f * __builtin_amdgcn_rcpf(1.f + __builtin_amdgcn_exp2f(2.8853900817779268f * x));
}

__device__ __forceinline__ void gload_lds16(const void* g, void* l) {
  __builtin_amdgcn_global_load_lds((const AS1 unsigned int*)g,
                                   (AS3 unsigned int*)l, 16, 0, 0);
}

// ---------------- prep: transpose + f32->f16 (Wk and Wr) -------------------
__global__ __launch_bounds__(256) void transpose_f16(
    const float* __restrict__ Wk, const float* __restrict__ Wr,
    _Float16* __restrict__ WkT, _Float16* __restrict__ WrT)
{
  __shared__ float tile[32][33];
  int b = blockIdx.x;
  const float* in = Wk; _Float16* outp = WkT;
  if (b >= 3072) { b -= 3072; in = Wr; outp = WrT; }
  const int n0 = (b % 96) * 32;
  const int k0 = (b / 96) * 32;
  const int tx = threadIdx.x & 31, ty = threadIdx.x >> 5;
#pragma unroll
  for (int i = 0; i < 32; i += 8)
    tile[ty + i][tx] = in[(size_t)(k0 + ty + i) * N3_ + n0 + tx];
  __syncthreads();
#pragma unroll
  for (int i = 0; i < 32; i += 8)
    outp[(size_t)(n0 + ty + i) * D_ + k0 + tx] = (_Float16)tile[tx][ty + i];
}

// ---------------- prep: x -> f16, h0 -> BOTH h16 buffers, c0 -> cst --------
__global__ void convert_inputs(const f32x4* __restrict__ x, const f32x4* __restrict__ h0,
                               const f32x4* __restrict__ c0,
                               half4* __restrict__ xh, half4* __restrict__ h16a,
                               half4* __restrict__ h16b, f32x4* __restrict__ cst)
{
  const int NX = (B_ * L_ * D_) / 4;
  const int NH = (B_ * D_) / 4;
  for (int i = blockIdx.x * blockDim.x + threadIdx.x; i < NX + NH;
       i += gridDim.x * blockDim.x) {
    if (i < NX) {
      xh[i] = __builtin_convertvector(x[i], half4);
    } else {
      const int k = i - NX;
      half4 v = __builtin_convertvector(h0[k], half4);
      h16a[k] = v;
      h16b[k] = v;
      cst[k] = c0[k];          // re-seed c every call (in-place updates)
    }
  }
}

// ---------------- xproj GEMM (R7-fixed swizzle, replay-proven) -------------
__global__ __launch_bounds__(256) void gemm_xproj(
    const _Float16* __restrict__ A,    // [32768][1024]
    const _Float16* __restrict__ BT,   // [3072][1024]
    _Float16* __restrict__ C)          // [32768][3072] f16
{
  __shared__ _Float16 As[128 * 32];
  __shared__ _Float16 Bs[128 * 32];
  const int tid = threadIdx.x, wave = tid >> 6, lane = tid & 63;
  const int mt = blockIdx.x / 24, ntile = blockIdx.x % 24;
  const int m0 = mt * 128, n0 = ntile * 128;
  const int l15 = lane & 15, l4h = lane >> 4;
  const int wm = (wave >> 1) * 64, wn = (wave & 1) * 64;

  const int c0i = wave * 2;
  const int lrow = lane >> 2;                       // 0..15 within chunk
  const int skel = 8 * ((lane & 3) ^ (lrow & 3));   // 2-bit XOR, in-bounds

  f32x4 acc[4][4];
#pragma unroll
  for (int i = 0; i < 4; ++i)
#pragma unroll
    for (int j = 0; j < 4; ++j) { f32x4 z = {0.f,0.f,0.f,0.f}; acc[i][j] = z; }

  for (int kk = 0; kk < 32; ++kk) {
    __syncthreads();
#pragma unroll
    for (int i = 0; i < 2; ++i) {
      const int c = c0i + i;
      const int row = c * 16 + lrow;
      gload_lds16(A  + (((size_t)(m0 + row)) << 10) + (kk << 5) + skel, &As[c << 9]);
      gload_lds16(BT + (((size_t)(n0 + row)) << 10) + (kk << 5) + skel, &Bs[c << 9]);
    }
    __syncthreads();
    half8 af[4], bf[4];
#pragma unroll
    for (int i = 0; i < 4; ++i) {
      const int ar = wm + i * 16 + l15;
      af[i] = *(const half8*)&As[(ar << 5) + ((l4h ^ (ar & 3)) << 3)];
      const int br = wn + i * 16 + l15;
      bf[i] = *(const half8*)&Bs[(br << 5) + ((l4h ^ (br & 3)) << 3)];
    }
#pragma unroll
    for (int i = 0; i < 4; ++i)
#pragma unroll
      for (int j = 0; j < 4; ++j)
        acc[i][j] = __builtin_amdgcn_mfma_f32_16x16x32_f16(af[i], bf[j], acc[i][j], 0, 0, 0);
  }
#pragma unroll
  for (int i = 0; i < 4; ++i) {
    const int row = m0 + wm + i * 16 + l4h * 4;
#pragma unroll
    for (int j = 0; j < 4; ++j) {
      const int col = n0 + wn + j * 16 + l15;
      _Float16* cp = C + (size_t)row * N3_ + col;
#pragma unroll
      for (int r = 0; r < 4; ++r)
        __builtin_nontemporal_store((_Float16)acc[i][j][r], cp + (size_t)r * N3_);
    }
  }
}

// ---------------- one scan step (kernel boundary = barrier) ----------------
// 256 WGs = 4 b-groups x 64 d-slices (16 cols); 4 waves own K-slices of 256.
__global__ __launch_bounds__(256) void lstm_step(
    const _Float16* __restrict__ WrT,   // [3072][1024]
    const _Float16* __restrict__ xproj, // [B*L][3072]
    float*          __restrict__ cst,   // [64][1024] in-place
    float*          __restrict__ out,   // [64][512][1024]
    const _Float16* __restrict__ hc,    // h_t
    _Float16*       __restrict__ hn,    // h_{t+1}
    int t)
{
  const int tid = threadIdx.x, wave = tid >> 6, lane = tid & 63;
  const int bid = blockIdx.x;
  const int grp = bid & 3;
  const int ord = bid >> 2;          // 0..63
  const int b0 = grp * 16;
  const int d0 = ord * 16;
  const int l15 = lane & 15, l4h = lane >> 4;
  const int kbase = wave * 256;

  // Wr fragments (plain loads; L2-hot after step 0)
  half8 Wrf[3][8];
#pragma unroll
  for (int g = 0; g < 3; ++g) {
    const _Float16* rr = WrT + (size_t)(g * D_ + d0 + l15) * D_ + kbase + l4h * 8;
#pragma unroll
    for (int kt = 0; kt < 8; ++kt) Wrf[g][kt] = *(const half8*)(rr + kt * 32);
  }

  // h fragments
  half8 af[8];
  const _Float16* hrow = hc + (size_t)(b0 + l15) * D_ + kbase + l4h * 8;
#pragma unroll
  for (int kt = 0; kt < 8; ++kt) af[kt] = *(const half8*)(hrow + kt * 32);

  f32x4 acc[3];
#pragma unroll
  for (int g = 0; g < 3; ++g) { f32x4 z = {0.f,0.f,0.f,0.f}; acc[g] = z; }
#pragma unroll
  for (int kt = 0; kt < 8; ++kt)
#pragma unroll
    for (int g = 0; g < 3; ++g)
      acc[g] = __builtin_amdgcn_mfma_f32_16x16x32_f16(af[kt], Wrf[g][kt], acc[g], 0, 0, 0);

  __shared__ float part[4][48][20];
#pragma unroll
  for (int g = 0; g < 3; ++g)
    *(f32x4*)&part[wave][g * 16 + l15][l4h * 4] = acc[g];
  __syncthreads();

  const int rb = tid >> 4, rd = tid & 15;
  const size_t xrow = ((size_t)(b0 + rb) * L_ + t) * N3_ + d0 + rd;
  float fv = (float)xproj[xrow];
  float ov = (float)xproj[xrow + D_];
  float gv = (float)xproj[xrow + 2 * D_];
#pragma unroll
  for (int w = 0; w < 4; ++w) {
    fv += part[w][rd][rb];
    ov += part[w][16 + rd][rb];
    gv += part[w][32 + rd][rb];
  }
  const size_t cidx = (size_t)(b0 + rb) * D_ + d0 + rd;
  float c = cst[cidx];
  const float sf = sigmoidf_fast(fv);
  c = c * sf + (1.f - sf) * tanhf_fast(gv);
  const float h = sigmoidf_fast(ov) * tanhf_fast(c);
  cst[cidx] = c;
  hn[cidx] = (_Float16)h;
  out[((size_t)(b0 + rb) * L_ + t) * D_ + d0 + rd] = h;
}

// ---------------------------------------------------------------------------
extern "C" void kernel_launch(void* const* d_in, const int* in_sizes, int n_in,
                              void* d_out, int out_size, void* d_ws, size_t ws_size,
                              hipStream_t stream) {
  const float* x  = (const float*)d_in[0];
  const float* Wk = (const float*)d_in[1];
  const float* Wr = (const float*)d_in[2];
  const float* c0 = (const float*)d_in[3];
  const float* h0 = (const float*)d_in[4];
  float* out = (float*)d_out;

  char* ws = (char*)d_ws;
  _Float16* WkT   = (_Float16*)(ws + WKT_OFF);
  _Float16* WrT   = (_Float16*)(ws + WRT_OFF);
  _Float16* xh    = (_Float16*)(ws + XH_OFF);
  _Float16* h16   = (_Float16*)(ws + H16_OFF);
  float*    cst   = (float*)(ws + CST_OFF);
  _Float16* xproj = (_Float16*)(ws + XPROJ_OFF);

  hipLaunchKernelGGL(transpose_f16, dim3(6144), dim3(256), 0, stream,
                     Wk, Wr, WkT, WrT);
  hipLaunchKernelGGL(convert_inputs, dim3(2048), dim3(256), 0, stream,
                     (const f32x4*)x, (const f32x4*)h0, (const f32x4*)c0,
                     (half4*)xh, (half4*)h16, (half4*)(h16 + B_ * D_),
                     (f32x4*)cst);
  hipLaunchKernelGGL(gemm_xproj, dim3(6144), dim3(256), 0, stream,
                     xh, WkT, xproj);

  for (int t = 0; t < L_; ++t) {
    _Float16* hc = h16 + (size_t)(t & 1) * (B_ * D_);
    _Float16* hn = h16 + (size_t)((t + 1) & 1) * (B_ * D_);
    hipLaunchKernelGGL(lstm_step, dim3(256), dim3(256), 0, stream,
                       WrT, xproj, cst, out, hc, hn, t);
  }
}